// Round 7
// baseline (329.806 us; speedup 1.0000x reference)
//
#include <hip/hip_runtime.h>

typedef __bf16 bf16;
typedef bf16 bf16x8 __attribute__((ext_vector_type(8)));
typedef bf16 bf16x4 __attribute__((ext_vector_type(4)));
typedef float f32x4 __attribute__((ext_vector_type(4)));

#define MFMA16(a, b, c) __builtin_amdgcn_mfma_f32_16x16x32_bf16((a), (b), (c), 0, 0, 0)

__device__ __forceinline__ void gload_lds16(const bf16* g, bf16* l) {
  __builtin_amdgcn_global_load_lds(
      (const __attribute__((address_space(1))) void*)g,
      (__attribute__((address_space(3))) void*)l, 16, 0, 0);
}

template <int N>
__device__ __forceinline__ void lgkm_fence() {
  if constexpr (N == 0) asm volatile("s_waitcnt lgkmcnt(0)" ::: "memory");
  else if constexpr (N == 4) asm volatile("s_waitcnt lgkmcnt(4)" ::: "memory");
  else if constexpr (N == 8) asm volatile("s_waitcnt lgkmcnt(8)" ::: "memory");
  else if constexpr (N == 12) asm volatile("s_waitcnt lgkmcnt(12)" ::: "memory");
  __builtin_amdgcn_sched_barrier(0);
}
__device__ __forceinline__ void bar_fence() {
  __builtin_amdgcn_sched_barrier(0);
  __builtin_amdgcn_s_barrier();
}

// ---------------------------------------------------------------------------
// All fp32 -> bf16 conversions in ONE launch (segment-switch on flat index).
// Segments (float4 units): hid 2097152 | Wq 1048576 | Wk 524288 | Wv 524288
// | Wo 1048576. Total 5242880 -> grid 20480 x 256.
// ---------------------------------------------------------------------------
__global__ __launch_bounds__(256) void cvt_all(const float* __restrict__ hid,
                                               const float* __restrict__ wq,
                                               const float* __restrict__ wk,
                                               const float* __restrict__ wv,
                                               const float* __restrict__ wo,
                                               bf16* __restrict__ xbf,
                                               bf16* __restrict__ wcat,
                                               bf16* __restrict__ wob) {
  int j = blockIdx.x * 256 + threadIdx.x;
  const float* src;
  bf16* dst;
  if (j < 2097152) { src = hid; dst = xbf; }
  else {
    j -= 2097152;
    if (j < 1048576) { src = wq; dst = wcat; }
    else {
      j -= 1048576;
      if (j < 524288) { src = wk; dst = wcat + 4194304; }
      else {
        j -= 524288;
        if (j < 524288) { src = wv; dst = wcat + 6291456; }
        else { j -= 524288; src = wo; dst = wob; }
      }
    }
  }
  float4 v = ((const float4*)src)[j];
  bf16x4 o;
  o[0] = (bf16)v.x; o[1] = (bf16)v.y; o[2] = (bf16)v.z; o[3] = (bf16)v.w;
  ((bf16x4*)dst)[j] = o;
}

// ---------------------------------------------------------------------------
// Pipelined GEMM C = A * B^T (round-2 schedule, best measured: 949 TF).
// BK=64, 2-slot LDS dbuf, 4 quadrant-phases/tile, cross-phase ds_reads with
// counted lgkm waits. NSPLIT>1: split-K — grid = NSPLIT*nwg, blocks with
// split s compute K in [s*K/NSPLIT, (s+1)*K/NSPLIT) and write to C0/C1.
// A/B row stride is always the full K.
// ---------------------------------------------------------------------------
template <int BM, int BN, int MT, int NTT, int NSPLIT, typename OutT>
__global__ __launch_bounds__(512, 2) void gemm_pipe(const bf16* __restrict__ A,
                                                    const bf16* __restrict__ B,
                                                    OutT* __restrict__ C0,
                                                    OutT* __restrict__ C1,
                                                    int M, int N, int K) {
  constexpr int MH = MT / 2, NH = NTT / 2;
  constexpr int ASLOT = BM * 64;           // elements per A slot
  constexpr int BSLOT = BN * 64;
  constexpr int NLA = BM / 64, NLB = BN / 64;
  __shared__ __align__(16) bf16 SA[2 * ASLOT];
  __shared__ __align__(16) bf16 SB[2 * BSLOT];

  const int tid = threadIdx.x;
  const int w = tid >> 6, lane = tid & 63;
  const int l15 = lane & 15, quad = lane >> 4;
  const int wr = w >> 2, wc = w & 3;       // 2 x 4 waves

  const int nbx = N / BN;
  const int nwg = (M / BM) * nbx;
  int bx = (int)blockIdx.x;
  int split = 0;
  if constexpr (NSPLIT > 1) { split = bx / nwg; bx -= split * nwg; }
  const int Keff = K / NSPLIT;
  const int NTILES = Keff >> 6;
  OutT* __restrict__ C = (split ? C1 : C0);
  const bf16* __restrict__ Ab = A + (size_t)split * Keff;
  const bf16* __restrict__ Bb = B + (size_t)split * Keff;

  // XCD-chunked bijective block swizzle (nwg % 8 == 0)
  const int wg = (bx & 7) * (nwg >> 3) + (bx >> 3);
  const int bm0 = (wg / nbx) * BM;
  const int bn0 = (wg % nbx) * BN;

  // Staging: thread -> LDS slot (tid + i*512); slot = row*8 + p,
  // stored granule = p ^ (row&7) (involution, conflict-free reads).
  const int r0 = tid >> 3;
  const int sg = (tid & 7) ^ ((tid >> 3) & 7);
  unsigned aoffg[NLA], boffg[NLB];
#pragma unroll
  for (int i = 0; i < NLA; ++i)
    aoffg[i] = (unsigned)((bm0 + r0 + i * 64) * K + sg * 8);
#pragma unroll
  for (int i = 0; i < NLB; ++i)
    boffg[i] = (unsigned)((bn0 + r0 + i * 64) * K + sg * 8);

  // Fragment read byte offsets: row*128 + p(kk)*16, p = (kk*4+quad)^(l15&7).
  const int xl = l15 & 7;
  const int p0 = quad ^ xl;
  const int baseA0 = (wr * (MT * 16) + l15) * 128 + p0 * 16;
  const int baseA1 = (wr * (MT * 16) + l15) * 128 + ((p0 ^ 4) * 16);
  const int baseB0 = (wc * (NTT * 16) + l15) * 128 + p0 * 16;
  const int baseB1 = (wc * (NTT * 16) + l15) * 128 + ((p0 ^ 4) * 16);
  const char* saB = (const char*)&SA[0];
  const char* sbB = (const char*)&SB[0];

  f32x4 acc[MT][NTT] = {};
  bf16x8 As[2][MH][2];   // set0 = Aq0 (rows half 0), set1 = Aq1
  bf16x8 Bs[2][NH][2];   // sets alternate with tile parity

#define LDA_(SL, H, DST)                                                        \
  _Pragma("unroll") for (int mt = 0; mt < MH; ++mt) {                           \
    (DST)[mt][0] = *(const bf16x8*)(saB + (SL) * (ASLOT * 2) + baseA0 +         \
                                    ((H) * MH + mt) * 2048);                    \
    (DST)[mt][1] = *(const bf16x8*)(saB + (SL) * (ASLOT * 2) + baseA1 +         \
                                    ((H) * MH + mt) * 2048);                    \
  }
#define LDB_(SL, G, DST)                                                        \
  _Pragma("unroll") for (int nt = 0; nt < NH; ++nt) {                           \
    (DST)[nt][0] = *(const bf16x8*)(sbB + (SL) * (BSLOT * 2) + baseB0 +         \
                                    ((G) * NH + nt) * 2048);                    \
    (DST)[nt][1] = *(const bf16x8*)(sbB + (SL) * (BSLOT * 2) + baseB1 +         \
                                    ((G) * NH + nt) * 2048);                    \
  }
#define QMFMA_(AS, BS, MHI, NHI)                                                \
  __builtin_amdgcn_s_setprio(1);                                                \
  _Pragma("unroll") for (int mt = 0; mt < MH; ++mt)                             \
      _Pragma("unroll") for (int nt = 0; nt < NH; ++nt) {                       \
    acc[(MHI) * MH + mt][(NHI) * NH + nt] = MFMA16(                             \
        (AS)[mt][0], (BS)[nt][0], acc[(MHI) * MH + mt][(NHI) * NH + nt]);       \
    acc[(MHI) * MH + mt][(NHI) * NH + nt] = MFMA16(                             \
        (AS)[mt][1], (BS)[nt][1], acc[(MHI) * MH + mt][(NHI) * NH + nt]);       \
  }                                                                             \
  __builtin_amdgcn_s_setprio(0);
#define STAGE_(SO, TS)                                                          \
  _Pragma("unroll") for (int i = 0; i < NLA; ++i)                               \
      gload_lds16(Ab + aoffg[i] + (TS) * 64, SA + (SO) * ASLOT + tid * 8 + i * 4096); \
  _Pragma("unroll") for (int i = 0; i < NLB; ++i)                               \
      gload_lds16(Bb + boffg[i] + (TS) * 64, SB + (SO) * BSLOT + tid * 8 + i * 4096);

#define GTILE_BODY(PAR, TS)                                                     \
  {                                                                             \
    constexpr int sl_ = (PAR), so_ = (PAR) ^ 1;                                 \
    constexpr int e0_ = (PAR), e1_ = (PAR) ^ 1;                                 \
    /* P1 */                                                                    \
    LDB_(sl_, 1, Bs[e1_]);                                                      \
    bar_fence();                                                                \
    lgkm_fence<NTT>();                                                          \
    if ((TS) < NTILES) { STAGE_(so_, (TS)); }                                   \
    QMFMA_(As[0], Bs[e0_], 0, 0);                                               \
    /* P2 */                                                                    \
    LDA_(sl_, 1, As[1]);                                                        \
    bar_fence();                                                                \
    lgkm_fence<MT>();                                                           \
    QMFMA_(As[0], Bs[e1_], 0, 1);                                               \
    /* P3 */                                                                    \
    LDB_(sl_, 0, Bs[e0_]);                                                      \
    asm volatile("s_waitcnt vmcnt(0)" ::: "memory");                            \
    bar_fence();                                                                \
    lgkm_fence<NTT>();                                                          \
    QMFMA_(As[1], Bs[e1_], 1, 1);                                               \
    /* P4 */                                                                    \
    LDA_(so_, 0, As[0]);                                                        \
    LDB_(so_, 0, Bs[e1_]);                                                      \
    bar_fence();                                                                \
    lgkm_fence<MT + NTT>();                                                     \
    QMFMA_(As[1], Bs[e0_], 1, 0);                                               \
  }

  // Prologue: stage tile 0, publish, pre-read Q1(0) operands.
  { STAGE_(0, 0); }
  asm volatile("s_waitcnt vmcnt(0)" ::: "memory");
  bar_fence();
  __builtin_amdgcn_sched_barrier(0);
  LDA_(0, 0, As[0]);
  LDB_(0, 0, Bs[0]);

  for (int t = 0; t < NTILES; t += 2) {
    GTILE_BODY(0, t + 1);
    GTILE_BODY(1, t + 2);
  }

#undef LDA_
#undef LDB_
#undef QMFMA_
#undef STAGE_
#undef GTILE_BODY

  // C write
#pragma unroll
  for (int mt = 0; mt < MT; ++mt)
#pragma unroll
    for (int nt = 0; nt < NTT; ++nt) {
      int row = bm0 + wr * (MT * 16) + mt * 16 + quad * 4;
      int col = bn0 + wc * (NTT * 16) + nt * 16 + l15;
#pragma unroll
      for (int r = 0; r < 4; ++r)
        C[(size_t)(row + r) * N + col] = (OutT)acc[mt][nt][r];
    }
}

// ---------------------------------------------------------------------------
// Split-K reduce: out = p0 + p1 (float4).
// ---------------------------------------------------------------------------
__global__ __launch_bounds__(256) void addred(const float4* __restrict__ p0,
                                              const float4* __restrict__ p1,
                                              float4* __restrict__ out, int n4) {
  int i = blockIdx.x * 256 + threadIdx.x;
  if (i < n4) {
    float4 a = p0[i], b = p1[i];
    float4 o;
    o.x = a.x + b.x; o.y = a.y + b.y; o.z = a.z + b.z; o.w = a.w + b.w;
    out[i] = o;
  }
}

// ---------------------------------------------------------------------------
// prep: vtrans (blocks 0..511) + RMSNorm/RoPE (blocks 512..25087) in one
// launch. Bodies identical to the previous separate kernels.
// ---------------------------------------------------------------------------
__global__ __launch_bounds__(256) void prep(const bf16* __restrict__ QKVb,
                                            const float* __restrict__ cosb,
                                            const float* __restrict__ sinb,
                                            const float* __restrict__ qw,
                                            const float* __restrict__ kw,
                                            bf16* __restrict__ Qb,
                                            bf16* __restrict__ Kb,
                                            bf16* __restrict__ Vtp) {
  __shared__ __align__(16) bf16 T[64 * 136];
  const int b = blockIdx.x;
  const int tid = threadIdx.x;
  if (b < 512) {
    // ---- V transpose + in-tile permute: Vtp[kvh][d][t*64+kp] =
    // V[t*64+sig(kp)][d], sig(kp) = (kp&3)*16 + (kp>>2).
    const int kvh = b >> 6;
    const int s0 = (b & 63) * 64;
    for (int g = tid; g < 1024; g += 256) {
      int s = g >> 4, cg = g & 15;
      *(bf16x8*)(T + s * 136 + cg * 8) =
          *(const bf16x8*)(QKVb + (size_t)(s0 + s) * 4096 + 3072 + kvh * 128 + cg * 8);
    }
    __syncthreads();
    for (int g = tid; g < 1024; g += 256) {
      int d = g >> 3, sg = g & 7;
      bf16x8 v;
#pragma unroll
      for (int j = 0; j < 8; j++) {
        int kp = sg * 8 + j;
        int s = (kp & 3) * 16 + (kp >> 2);
        v[j] = T[s * 136 + d];
      }
      *(bf16x8*)(Vtp + ((size_t)kvh * 128 + d) * 4096 + s0 + sg * 8) = v;
    }
  } else {
    // ---- RMSNorm + RoPE. Q prescaled by D^-0.5*log2(e) for fixed-max exp2
    // softmax (|score*log2e| <= 11.32*1.4427 < 17.3; MP = 12*log2(e)).
    const int wid = ((b - 512) * 256 + tid) >> 6;
    const int lane = tid & 63;
    const int s = wid / 24;
    const int h = wid % 24;
    const bool isq = (h < 16);
    const int col0 = isq ? h * 128 : 2048 + (h - 16) * 128;
    const float* wt = isq ? qw : kw;

    const bf16* row = QKVb + (size_t)s * 4096 + col0;
    float x1 = (float)row[lane];
    float x2 = (float)row[lane + 64];

    float ss = x1 * x1 + x2 * x2;
#pragma unroll
    for (int m = 32; m >= 1; m >>= 1) ss += __shfl_xor(ss, m, 64);
    float rs = rsqrtf(ss * (1.0f / 128.0f) + 1e-6f);

    float c = cosb[(size_t)s * 128 + lane];
    float sn = sinb[(size_t)s * 128 + lane];
    float xn1 = x1 * rs * wt[lane];
    float xn2 = x2 * rs * wt[lane + 64];
    float o1 = xn1 * c - xn2 * sn;
    float o2 = xn2 * c + xn1 * sn;
    const float scale = isq ? 0.12751652f : 1.0f;  // D^-0.5 * log2(e)
    o1 *= scale; o2 *= scale;

    bf16* dst = isq ? (Qb + ((size_t)h * 4096 + s) * 128)
                    : (Kb + ((size_t)(h - 16) * 4096 + s) * 128);
    dst[lane] = (bf16)o1;
    dst[lane + 64] = (bf16)o2;
  }
}

// ---------------------------------------------------------------------------
// Sliding-window GQA flash attention, pipelined (round-6 version).
// 256-q blocks, 512 threads (8 waves x 32 q), grid 256 = 1 block/CU.
// K/V double-buffered; counted vmcnt(4) + raw s_barrier per tile.
// ---------------------------------------------------------------------------
__global__ __launch_bounds__(512, 1) void attn_kernel(const bf16* __restrict__ Qb,
                                                      const bf16* __restrict__ Kb,
                                                      const bf16* __restrict__ Vtp,
                                                      bf16* __restrict__ Ob) {
  const int SEQ = 4096, W = 1024;
  const float MP = 17.312340f;  // 12 * log2(e)
  __shared__ __align__(16) bf16 Ks[2][64 * 128];   // [slot][key][d granule swz]
  __shared__ __align__(16) bf16 Vs[2][128 * 64];   // [slot][d][kp granule swz]
  __shared__ __align__(16) bf16 Ps[8][32 * 64];    // per-wave P, xor-swizzled

  const int id = blockIdx.x;
  const int kvh = id & 7, gq = (id >> 3) & 1, h = kvh * 2 + gq;
  const int qb0 = (id >> 4) * 256;
  const int tid = threadIdx.x, w = tid >> 6, lane = tid & 63;
  const int l15 = lane & 15, quad = lane >> 4;
  const int qw0 = qb0 + w * 32;

  bf16x8 qf[2][4];
#pragma unroll
  for (int m = 0; m < 2; m++) {
    const bf16* qp = Qb + ((size_t)h * SEQ + qw0 + m * 16 + l15) * 128 + quad * 8;
#pragma unroll
    for (int kb = 0; kb < 4; kb++) qf[m][kb] = *(const bf16x8*)(qp + kb * 32);
  }

  f32x4 o[2][8] = {};
  f32x4 lr[2] = {};
  bf16* pw = &Ps[w][0];
  const bf16* kbase = Kb + (size_t)kvh * SEQ * 128;
  const bf16* vbase = Vtp + (size_t)kvh * 128 * SEQ;

  int jmin = qb0 - (W - 1); if (jmin < 0) jmin = 0;
  const int kt0 = jmin >> 6, kt1 = (qb0 + 255) >> 6;

#define ASTAGE(KT, SL)                                                          \
  do {                                                                          \
    const int k0_ = (KT) * 64;                                                  \
    _Pragma("unroll") for (int i_ = 0; i_ < 2; ++i_) {                          \
      int slot = i_ * 512 + tid;                                                \
      int key = slot >> 4, gg = slot & 15;                                      \
      int gsw = gg ^ (key & 7);                                                 \
      gload_lds16(kbase + (size_t)(k0_ + key) * 128 + gsw * 8,                  \
                  &Ks[SL][0] + slot * 8);                                       \
    }                                                                           \
    _Pragma("unroll") for (int i_ = 0; i_ < 2; ++i_) {                          \
      int slot = i_ * 512 + tid;                                                \
      int d = slot >> 3, gg = slot & 7;                                         \
      int gsw = gg ^ (d & 7);                                                   \
      gload_lds16(vbase + (size_t)d * SEQ + k0_ + gsw * 8,                      \
                  &Vs[SL][0] + slot * 8);                                       \
    }                                                                           \
  } while (0)

  ASTAGE(kt0, 0);

  for (int kt = kt0; kt <= kt1; ++kt) {
    const int sl = (kt - kt0) & 1;
    if (kt < kt1) {
      ASTAGE(kt + 1, sl ^ 1);
      asm volatile("s_waitcnt vmcnt(4)" ::: "memory");
    } else {
      asm volatile("s_waitcnt vmcnt(0)" ::: "memory");
    }
    __builtin_amdgcn_s_barrier();

    const int k0 = kt * 64;
    const bf16* ks = &Ks[sl][0];
    const bf16* vs = &Vs[sl][0];
    const bool alive = (k0 <= qw0 + 31) && (k0 + 63 > qw0 - W);
    if (alive) {
      const bool full = (k0 + 63 <= qw0) && (k0 > qw0 + 31 - W);
      f32x4 s[2][4] = {};
#pragma unroll
      for (int c = 0; c < 4; c++) {
        const int key = c * 16 + l15;
        bf16x8 kf[4];
#pragma unroll
        for (int kb = 0; kb < 4; kb++)
          kf[kb] = *(const bf16x8*)(ks + key * 128 + (((kb * 4 + quad) ^ (key & 7)) << 3));
        __builtin_amdgcn_s_setprio(1);
#pragma unroll
        for (int kb = 0; kb < 4; kb++) {
          s[0][c] = MFMA16(qf[0][kb], kf[kb], s[0][c]);
          s[1][c] = MFMA16(qf[1][kb], kf[kb], s[1][c]);
        }
        __builtin_amdgcn_s_setprio(0);
      }
#pragma unroll
      for (int m = 0; m < 2; m++)
#pragma unroll
        for (int r = 0; r < 4; r++) {
          float p[4];
          if (full) {
#pragma unroll
            for (int c = 0; c < 4; c++) p[c] = __builtin_amdgcn_exp2f(s[m][c][r] - MP);
          } else {
            const int i_ = qw0 + m * 16 + quad * 4 + r;
#pragma unroll
            for (int c = 0; c < 4; c++) {
              int j = k0 + c * 16 + l15;
              p[c] = (j <= i_ && j > i_ - W) ? __builtin_amdgcn_exp2f(s[m][c][r] - MP) : 0.0f;
            }
          }
          lr[m][r] += p[0] + p[1] + p[2] + p[3];
          bf16x4 pk;
          pk[0] = (bf16)p[0]; pk[1] = (bf16)p[1]; pk[2] = (bf16)p[2]; pk[3] = (bf16)p[3];
          const int qrow = m * 16 + quad * 4 + r;
          *(bf16x4*)(pw + qrow * 64 + (((l15 >> 1) ^ (qrow & 7)) << 3) + (l15 & 1) * 4) = pk;
        }
      asm volatile("s_waitcnt lgkmcnt(0)" ::: "memory");
      bf16x8 pf[2][2];
#pragma unroll
      for (int m = 0; m < 2; m++)
#pragma unroll
        for (int kb = 0; kb < 2; kb++)
          pf[m][kb] = *(const bf16x8*)(pw + (m * 16 + l15) * 64 +
                                       (((kb * 4 + quad) ^ (l15 & 7)) << 3));
#pragma unroll
      for (int n = 0; n < 8; n++) {
        const int d = n * 16 + l15;
        bf16x8 vf0 = *(const bf16x8*)(vs + d * 64 + ((quad ^ (l15 & 7)) << 3));
        bf16x8 vf1 = *(const bf16x8*)(vs + d * 64 + (((4 + quad) ^ (l15 & 7)) << 3));
        __builtin_amdgcn_s_setprio(1);
        o[0][n] = MFMA16(pf[0][0], vf0, o[0][n]);
        o[0][n] = MFMA16(pf[0][1], vf1, o[0][n]);
        o[1][n] = MFMA16(pf[1][0], vf0, o[1][n]);
        o[1][n] = MFMA16(pf[1][1], vf1, o[1][n]);
        __builtin_amdgcn_s_setprio(0);
      }
    }
    __builtin_amdgcn_s_barrier();
  }
#undef ASTAGE

  float linv[2][4];
#pragma unroll
  for (int m = 0; m < 2; m++)
#pragma unroll
    for (int r = 0; r < 4; r++) {
      float v = lr[m][r];
      v += __shfl_xor(v, 1, 64);
      v += __shfl_xor(v, 2, 64);
      v += __shfl_xor(v, 4, 64);
      v += __shfl_xor(v, 8, 64);
      linv[m][r] = 1.0f / v;
    }
#pragma unroll
  for (int m = 0; m < 2; m++)
#pragma unroll
    for (int n = 0; n < 8; n++)
#pragma unroll
      for (int r = 0; r < 4; r++) {
        int i_ = qw0 + m * 16 + quad * 4 + r;
        Ob[(size_t)i_ * 2048 + h * 128 + n * 16 + l15] = (bf16)(o[m][n][r] * linv[m][r]);
      }
}

// ---------------------------------------------------------------------------
// Orchestration. Workspace (112 MB):
//   0..16   Xbf (gemm1 A); Vtp [8][128][4096] reuses 0..8 after gemm1;
//           P1 (32 MB f32) reuses 0..32 after attn
//   16..32  Wcat
//   32..40  Wob
//   40..72  QKVb; P0 (32 MB f32) reuses after prep
//   72..88  Qb   88..96 Kb   96..112 Ob
// ---------------------------------------------------------------------------
extern "C" void kernel_launch(void* const* d_in, const int* in_sizes, int n_in,
                              void* d_out, int out_size, void* d_ws, size_t ws_size,
                              hipStream_t stream) {
  const float* hid  = (const float*)d_in[0];
  const float* cosb = (const float*)d_in[1];
  const float* sinb = (const float*)d_in[2];
  const float* Wq   = (const float*)d_in[3];
  const float* Wk   = (const float*)d_in[4];
  const float* Wv   = (const float*)d_in[5];
  const float* Wo   = (const float*)d_in[6];
  const float* qw   = (const float*)d_in[7];
  const float* kw   = (const float*)d_in[8];

  if (ws_size < (size_t)(112u) * 1024u * 1024u) return;

  char* ws = (char*)d_ws;
  bf16* Xbf  = (bf16*)(ws);
  bf16* Vtp  = (bf16*)(ws);
  float* P1  = (float*)(ws);
  bf16* Wcat = (bf16*)(ws + (16u << 20));
  bf16* Wob  = (bf16*)(ws + (32u << 20));
  bf16* QKVb = (bf16*)(ws + (40u << 20));
  float* P0  = (float*)(ws + (40u << 20));
  bf16* Qb   = (bf16*)(ws + (72u << 20));
  bf16* Kb   = (bf16*)(ws + (88u << 20));
  bf16* Ob   = (bf16*)(ws + (96u << 20));

  cvt_all<<<20480, 256, 0, stream>>>(hid, Wq, Wk, Wv, Wo, Xbf, Wcat, Wob);

  gemm_pipe<256, 256, 8, 4, 1, bf16><<<256, 512, 0, stream>>>(
      Xbf, Wcat, QKVb, QKVb, 4096, 4096, 2048);

  prep<<<25088, 256, 0, stream>>>(QKVb, cosb, sinb, qw, kw, Qb, Kb, Vtp);

  attn_kernel<<<256, 512, 0, stream>>>(Qb, Kb, Vtp, Ob);

  // Output projection: split-K x2 (blocks 0..127 -> P0 with K in [0,1024),
  // blocks 128..255 -> P1 with K in [1024,2048)), then reduce.
  gemm_pipe<256, 256, 8, 4, 2, float><<<256, 512, 0, stream>>>(
      Ob, Wob, P0, P1, 4096, 2048, 2048);
  addred<<<8192, 256, 0, stream>>>((const float4*)P0, (const float4*)P1,
                                   (float4*)d_out, 2097152);
}